// Round 8
// baseline (162.839 us; speedup 1.0000x reference)
//
#include <hip/hip_runtime.h>
#include <stdint.h>

typedef __bf16 bf16x8 __attribute__((ext_vector_type(8)));
typedef float  f32x4  __attribute__((ext_vector_type(4)));
typedef uint32_t u32x4 __attribute__((ext_vector_type(4)));

__device__ __forceinline__ uint16_t f2bf(float f) {
    uint32_t u = __builtin_bit_cast(uint32_t, f);
    u += 0x7FFFu + ((u >> 16) & 1u);          // round-to-nearest-even
    return (uint16_t)(u >> 16);
}

// ---------------------------------------------------------------------------
// Kernel 1: Q [b][c 256][i 32][j 32] f32 -> Qt [b][ih 2][j 32][ch 32][il 16][8] bf16
//   where c = ch*8 + t, i = ih*16 + il.  Corr's B-fragment load = 1 KB contiguous.
//   Also zeroes the output tensor (replaces the separate hipMemsetAsync).
// ---------------------------------------------------------------------------
__global__ __launch_bounds__(256) void qtrans_kernel(const float* __restrict__ Q,
                                                     uint16_t* __restrict__ Qt,
                                                     float* __restrict__ out) {
    // T[c8 8][i 32][j 33] f32, c8-stride 1064 so bank = 8*c8 + i + j
    __shared__ float T[8 * 1064];
    const int ch = blockIdx.x, b = blockIdx.y;
    const int tid = threadIdx.x;

    // fold in out-zeroing: 512 blocks x 256 threads = 131072 >= 67600
    {
        int g = (b * 32 + ch) * 256 + tid;
        if (g < 67600) out[g] = 0.f;
    }

    const float* src = Q + ((size_t)(b * 256 + ch * 8)) * 1024;
    #pragma unroll
    for (int it = 0; it < 32; ++it) {                  // 8192 f32, coalesced
        int r = tid + it * 256;
        int c8 = r >> 10, rem = r & 1023;
        T[c8 * 1064 + (rem >> 5) * 33 + (rem & 31)] = src[(size_t)c8 * 1024 + rem];
    }
    __syncthreads();

    uint32_t* dst = (uint32_t*)Qt;                     // write bf16 pairs
    #pragma unroll
    for (int it = 0; it < 16; ++it) {                  // 4096 pairs
        int o2 = tid + it * 256;
        int t  = (o2 & 3) * 2;
        int il = (o2 >> 2) & 15;
        int j  = (o2 >> 6) & 31;
        int ih = (o2 >> 11) & 1;
        float v0 = T[t * 1064 + (ih * 16 + il) * 33 + j];
        float v1 = T[(t + 1) * 1064 + (ih * 16 + il) * 33 + j];
        uint32_t pk = (uint32_t)f2bf(v0) | ((uint32_t)f2bf(v1) << 16);
        size_t oi = ((((size_t)(b * 2 + ih) * 32 + j) * 32 + ch) * 16 + il) * 4 + (t >> 1);
        dst[oi] = pk;
    }
}

// ---------------------------------------------------------------------------
// Kernel 2: round-7 structure (grid 1024, b=bid&15 XCD swizzle, 40 KB LDS,
// 4 blocks/CU, B-fragment register ping-pong) + ONE new delta:
//   * A-fragment (LDS) ping-pong one body ahead.  Round-7 evidence: B-prefetch
//     alone gave only +4% -- the residual exposed latency is the 5 ds_read_b128
//     issued immediately before their consuming MFMAs (~170 cy/body/wave).
//     A depends only on post-barrier-stable LDS, so it is fully prefetchable.
//   * sched_barrier(0) pins both prefetch clusters above the MFMA block
//     (round-1 lesson: without it hipcc sinks loads to point-of-use).
// REGISTER DISCIPLINE (round-2 lesson): acc 40 + A 2x20 + B 2x16 + addr ~10
// ~= 122 <= 128 at 4 waves/SIMD.  Spill signature = VGPR 128 + WRITE >> 9 MB.
// ---------------------------------------------------------------------------
__global__ __launch_bounds__(256, 4) void corr_kernel(const float* __restrict__ S,
                                                      const uint16_t* __restrict__ Qt,
                                                      float* __restrict__ out) {
    __shared__ __align__(16) char smem[40960];         // 40 KB -> 4 blocks/CU
    uint16_t* S_l = (uint16_t*)smem;                   // [ch][row]: idx = ch*640 + row*8
    float*    Pw  = (float*)smem;                      // overlay: [4][iv 32][x 80]

    const int bid = blockIdx.x;
    const int b = bid & 15, d = bid >> 4;
    const int tid = threadIdx.x, wave = tid >> 6, lane = tid & 63;
    const int l15 = lane & 15, l4 = lane >> 4;

    // ---- zero-fill pad rows 0..15 for all ch (8 KB)
    {
        const u32x4 z = {};
        for (int zi = tid; zi < 512; zi += 256) {
            int ch = zi >> 4, r = zi & 15;
            *(u32x4*)&S_l[ch * 640 + r * 8] = z;
        }
    }
    // ---- stage S[b,:,d,:] -> S_l[ch][sx+16] (bf16). Writes lane-contiguous.
    {
        const int sx = tid & 63, w = tid >> 6;
        const float* sp = S + ((size_t)b * 256) * 4096 + (size_t)d * 64;
        #pragma unroll
        for (int k = 0; k < 8; ++k) {
            int ch = w * 8 + k;
            float v[8];
            #pragma unroll
            for (int cc = 0; cc < 8; ++cc)
                v[cc] = sp[(size_t)(ch * 8 + cc) * 4096 + sx];   // 256B coalesced
            u32x4 pk;
            #pragma unroll
            for (int q = 0; q < 4; ++q)
                pk[q] = (uint32_t)f2bf(v[2 * q]) | ((uint32_t)f2bf(v[2 * q + 1]) << 16);
            *(u32x4*)&S_l[ch * 640 + (sx + 16) * 8] = pk;        // contiguous 1KB/wave
        }
    }

    // ---- B-fragment base.  Body (jj,s): off = (wave+jj*4)*4096 + s*512.
    //      Fragments: +0 (ih0,j0a), +131072 (ih1,j0a), +65536 (ih0,j0b),
    //      +196608 (ih1,j0b).
    const uint16_t* Bb = Qt + (size_t)b * 262144 + l4 * 128 + l15 * 8;

    // prefetch body 0's B-fragments BEFORE the barrier (no LDS dependency)
    bf16x8 C0, C1, C2, C3;
    {
        const int s0 = (2 * wave) & 7;
        const uint16_t* p0 = Bb + wave * 4096 + s0 * 512;
        C0 = *(const bf16x8*)(p0);
        C1 = *(const bf16x8*)(p0 + 131072);
        C2 = *(const bf16x8*)(p0 + 65536);
        C3 = *(const bf16x8*)(p0 + 196608);
    }

    __syncthreads();

    // ---- prologue: A-fragments of body 0 (jj=0 -> j0a=wave, s=(2*wave)&7)
    bf16x8 Ac[5];
    {
        const int s0 = (2 * wave) & 7;
        const int chb = (s0 * 4 + l4) * 640;
        #pragma unroll
        for (int t = 0; t < 5; ++t) {
            int rr = wave + t * 16 + l15;              // <= 94
            rr = (rr < 80) ? rr : 0;                   // OOB -> zero-row
            Ac[t] = *(const bf16x8*)&S_l[chb + rr * 8];
        }
    }

    f32x4 acc[5][2] = {};

    #pragma unroll
    for (int n = 0; n < 32; ++n) {
        // ---- next body's coordinates (n=31 clamps to itself; results dead)
        const int nn = (n < 31) ? (n + 1) : 31;
        const int jn = nn >> 3;
        const int sn = ((nn & 7) + 2 * wave) & 7;      // per-wave s-rotation
        const int j0n = wave + jn * 4;

        // ---- issue NEXT body's B-loads (VMEM ping-pong)
        const uint16_t* pn = Bb + j0n * 4096 + sn * 512;
        bf16x8 N0 = *(const bf16x8*)(pn);
        bf16x8 N1 = *(const bf16x8*)(pn + 131072);
        bf16x8 N2 = *(const bf16x8*)(pn + 65536);
        bf16x8 N3 = *(const bf16x8*)(pn + 196608);

        // ---- issue NEXT body's A-reads (LDS ping-pong) -- removes the
        // per-body exposed ds_read latency that r7 left behind
        bf16x8 An[5];
        {
            const int chbn = (sn * 4 + l4) * 640;
            #pragma unroll
            for (int t = 0; t < 5; ++t) {
                int rr = j0n + t * 16 + l15;           // <= 94
                rr = (rr < 80) ? rr : 0;               // OOB -> zero-row
                An[t] = *(const bf16x8*)&S_l[chbn + rr * 8];
            }
        }
        __builtin_amdgcn_sched_barrier(0);             // pin prefetches above MFMAs

        // ---- 18 MFMAs on the CURRENT fragments (loaded one body ago)
        #pragma unroll
        for (int t = 0; t < 5; ++t) {
            acc[t][0] = __builtin_amdgcn_mfma_f32_16x16x32_bf16(Ac[t], C0, acc[t][0], 0, 0, 0);
            acc[t][1] = __builtin_amdgcn_mfma_f32_16x16x32_bf16(Ac[t], C1, acc[t][1], 0, 0, 0);
        }
        #pragma unroll
        for (int t = 1; t < 5; ++t) {
            acc[t - 1][0] = __builtin_amdgcn_mfma_f32_16x16x32_bf16(Ac[t], C2, acc[t - 1][0], 0, 0, 0);
            acc[t - 1][1] = __builtin_amdgcn_mfma_f32_16x16x32_bf16(Ac[t], C3, acc[t - 1][1], 0, 0, 0);
        }

        // ---- rotate ping-pong registers
        #pragma unroll
        for (int t = 0; t < 5; ++t) Ac[t] = An[t];
        C0 = N0; C1 = N1; C2 = N2; C3 = N3;
    }

    // ---- merge 4 wave-partials in LDS, then atomic-add into out
    __syncthreads();
    {
        float* pw = Pw + wave * 2560;                  // [iv 32][x 80]
        #pragma unroll
        for (int m = 0; m < 5; ++m)
            #pragma unroll
            for (int n = 0; n < 2; ++n)
                *(f32x4*)&pw[(n * 16 + l15) * 80 + m * 16 + l4 * 4] = acc[m][n];
    }
    __syncthreads();
    for (int e = tid; e < 65 * 32; e += 256) {
        int x = e % 65, i = e / 65;
        int y = d - i + 16;
        if ((unsigned)y < 65u) {
            float v = Pw[0 * 2560 + i * 80 + x] + Pw[1 * 2560 + i * 80 + x]
                    + Pw[2 * 2560 + i * 80 + x] + Pw[3 * 2560 + i * 80 + x];
            atomicAdd(out + ((size_t)b * 4225 + (size_t)y * 65 + x), v);
        }
    }
}

// ---------------------------------------------------------------------------
// fp32 fallback (only if workspace is too small) — slow but exact
// ---------------------------------------------------------------------------
__global__ __launch_bounds__(256) void naive_kernel(const float* __restrict__ Q,
                                                    const float* __restrict__ S,
                                                    float* __restrict__ out) {
    int gid = blockIdx.x * 256 + threadIdx.x;
    if (gid >= 67600) return;
    int b = gid / 4225, r = gid % 4225, y = r / 65, x = r % 65;
    int jlo = 16 - x; if (jlo < 0) jlo = 0;
    int jhi = 80 - x; if (jhi > 32) jhi = 32;
    float acc = 0.f;
    for (int c = 0; c < 256; ++c) {
        const float* Sb = S + ((size_t)(b * 256 + c)) * 4096;
        const float* Qb = Q + ((size_t)(b * 256 + c)) * 1024;
        for (int i = 0; i < 32; ++i) {
            int dd = y + i - 16;
            if ((unsigned)dd >= 64u) continue;
            const float* Sr = Sb + dd * 64 + (x - 16);
            const float* Qr = Qb + i * 32;
            for (int j = jlo; j < jhi; ++j) acc += Sr[j] * Qr[j];
        }
    }
    out[gid] = acc;
}

extern "C" void kernel_launch(void* const* d_in, const int* in_sizes, int n_in,
                              void* d_out, int out_size, void* d_ws, size_t ws_size,
                              hipStream_t stream) {
    (void)in_sizes; (void)n_in; (void)out_size;
    const float* Q = (const float*)d_in[0];   // [16,256,32,32] f32
    const float* S = (const float*)d_in[1];   // [16,256,64,64] f32
    float* out = (float*)d_out;               // [16,1,65,65] f32

    const size_t QT_BYTES = (size_t)16 * 2 * 32 * 32 * 16 * 8 * 2;  // 8,388,608

    if (ws_size < QT_BYTES) {
        naive_kernel<<<(67600 + 255) / 256, 256, 0, stream>>>(Q, S, out);
        return;
    }
    uint16_t* Qt = (uint16_t*)d_ws;

    qtrans_kernel<<<dim3(32, 16), 256, 0, stream>>>(Q, Qt, out);
    corr_kernel<<<1024, 256, 0, stream>>>(S, Qt, out);
}

// Round 9
// 131.447 us; speedup vs baseline: 1.2388x; 1.2388x over previous
//
#include <hip/hip_runtime.h>
#include <stdint.h>

typedef __bf16 bf16x8 __attribute__((ext_vector_type(8)));
typedef float  f32x4  __attribute__((ext_vector_type(4)));
typedef uint32_t u32x4 __attribute__((ext_vector_type(4)));

__device__ __forceinline__ uint16_t f2bf(float f) {
    uint32_t u = __builtin_bit_cast(uint32_t, f);
    u += 0x7FFFu + ((u >> 16) & 1u);          // round-to-nearest-even
    return (uint16_t)(u >> 16);
}

// ---------------------------------------------------------------------------
// Kernel 1: Q [b][c 256][i 32][j 32] f32 -> Qt [b][ih 2][j 32][ch 32][il 16][8] bf16
//   where c = ch*8 + t, i = ih*16 + il.  Corr's B-fragment load = 1 KB contiguous.
//   Also zeroes the output tensor (replaces the separate hipMemsetAsync).
// ---------------------------------------------------------------------------
__global__ __launch_bounds__(256) void qtrans_kernel(const float* __restrict__ Q,
                                                     uint16_t* __restrict__ Qt,
                                                     float* __restrict__ out) {
    // T[c8 8][i 32][j 33] f32, c8-stride 1064 so bank = 8*c8 + i + j
    __shared__ float T[8 * 1064];
    const int ch = blockIdx.x, b = blockIdx.y;
    const int tid = threadIdx.x;

    // fold in out-zeroing: 512 blocks x 256 threads = 131072 >= 67600
    {
        int g = (b * 32 + ch) * 256 + tid;
        if (g < 67600) out[g] = 0.f;
    }

    const float* src = Q + ((size_t)(b * 256 + ch * 8)) * 1024;
    #pragma unroll
    for (int it = 0; it < 32; ++it) {                  // 8192 f32, coalesced
        int r = tid + it * 256;
        int c8 = r >> 10, rem = r & 1023;
        T[c8 * 1064 + (rem >> 5) * 33 + (rem & 31)] = src[(size_t)c8 * 1024 + rem];
    }
    __syncthreads();

    uint32_t* dst = (uint32_t*)Qt;                     // write bf16 pairs
    #pragma unroll
    for (int it = 0; it < 16; ++it) {                  // 4096 pairs
        int o2 = tid + it * 256;
        int t  = (o2 & 3) * 2;
        int il = (o2 >> 2) & 15;
        int j  = (o2 >> 6) & 31;
        int ih = (o2 >> 11) & 1;
        float v0 = T[t * 1064 + (ih * 16 + il) * 33 + j];
        float v1 = T[(t + 1) * 1064 + (ih * 16 + il) * 33 + j];
        uint32_t pk = (uint32_t)f2bf(v0) | ((uint32_t)f2bf(v1) << 16);
        size_t oi = ((((size_t)(b * 2 + ih) * 32 + j) * 32 + ch) * 16 + il) * 4 + (t >> 1);
        dst[oi] = pk;
    }
}

// ---------------------------------------------------------------------------
// Kernel 2: round-7 structure (grid 1024, b=bid&15 XCD swizzle, 40 KB LDS,
// 4 blocks/CU, B-fragment register ping-pong one body ahead) with ONE delta:
//   * the hard sched_barrier(0) is replaced by a sched_group_barrier
//     prescription per body: {4 VMEM_READ, 5 DS_READ, 6 x (3 MFMA + 3 VALU)}.
//     Round-7 evidence: the hard fence kept loads early (good) but pushed
//     VALUBusy 16.8 -> 24 while MfmaUtil only +3 -- it forbade interleaving
//     the next body's address VALU into the MFMA shadow.  SGB keeps the
//     loads pinned at the body top AND fills the MFMA cluster with VALU.
// REGISTER DISCIPLINE (round-2/8 lessons): acc 40 AGPR + ~60 VGPR = 100 regs
// at 4 waves/SIMD.  Do NOT add a second A-fragment set (r8 spilled: WRITE
// 8.9 -> 51 MB) and do NOT raise the launch-bounds occupancy (r2).
// ---------------------------------------------------------------------------
__global__ __launch_bounds__(256, 4) void corr_kernel(const float* __restrict__ S,
                                                      const uint16_t* __restrict__ Qt,
                                                      float* __restrict__ out) {
    __shared__ __align__(16) char smem[40960];         // 40 KB -> 4 blocks/CU
    uint16_t* S_l = (uint16_t*)smem;                   // [ch][row]: idx = ch*640 + row*8
    float*    Pw  = (float*)smem;                      // overlay: [4][iv 32][x 80]

    const int bid = blockIdx.x;
    const int b = bid & 15, d = bid >> 4;
    const int tid = threadIdx.x, wave = tid >> 6, lane = tid & 63;
    const int l15 = lane & 15, l4 = lane >> 4;

    // ---- zero-fill pad rows 0..15 for all ch (8 KB)
    {
        const u32x4 z = {};
        for (int zi = tid; zi < 512; zi += 256) {
            int ch = zi >> 4, r = zi & 15;
            *(u32x4*)&S_l[ch * 640 + r * 8] = z;
        }
    }
    // ---- stage S[b,:,d,:] -> S_l[ch][sx+16] (bf16). Writes lane-contiguous.
    {
        const int sx = tid & 63, w = tid >> 6;
        const float* sp = S + ((size_t)b * 256) * 4096 + (size_t)d * 64;
        #pragma unroll
        for (int k = 0; k < 8; ++k) {
            int ch = w * 8 + k;
            float v[8];
            #pragma unroll
            for (int cc = 0; cc < 8; ++cc)
                v[cc] = sp[(size_t)(ch * 8 + cc) * 4096 + sx];   // 256B coalesced
            u32x4 pk;
            #pragma unroll
            for (int q = 0; q < 4; ++q)
                pk[q] = (uint32_t)f2bf(v[2 * q]) | ((uint32_t)f2bf(v[2 * q + 1]) << 16);
            *(u32x4*)&S_l[ch * 640 + (sx + 16) * 8] = pk;        // contiguous 1KB/wave
        }
    }

    // ---- B-fragment base.  Body (jj,s): off = (wave+jj*4)*4096 + s*512.
    //      Fragments: +0 (ih0,j0a), +131072 (ih1,j0a), +65536 (ih0,j0b),
    //      +196608 (ih1,j0b).
    const uint16_t* Bb = Qt + (size_t)b * 262144 + l4 * 128 + l15 * 8;

    // prefetch body 0's B-fragments BEFORE the barrier (no LDS dependency)
    bf16x8 C0, C1, C2, C3;
    {
        const int s0 = (2 * wave) & 7;
        const uint16_t* p0 = Bb + wave * 4096 + s0 * 512;
        C0 = *(const bf16x8*)(p0);
        C1 = *(const bf16x8*)(p0 + 131072);
        C2 = *(const bf16x8*)(p0 + 65536);
        C3 = *(const bf16x8*)(p0 + 196608);
    }

    __syncthreads();

    f32x4 acc[5][2] = {};

    #pragma unroll
    for (int n = 0; n < 32; ++n) {
        const int jj = n >> 3;
        const int s  = ((n & 7) + 2 * wave) & 7;       // per-wave s-rotation
        const int j0a = wave + jj * 4;                 // 0..15 ; j0b = j0a+16

        // ---- issue NEXT body's B-loads (ping-pong).  Branchless clamp:
        // n=31 re-loads body 31 (results dead afterwards).
        const int nn = (n < 31) ? (n + 1) : 31;
        const int jn = nn >> 3;
        const int sn = ((nn & 7) + 2 * wave) & 7;
        const uint16_t* pn = Bb + (wave + jn * 4) * 4096 + sn * 512;
        bf16x8 N0 = *(const bf16x8*)(pn);
        bf16x8 N1 = *(const bf16x8*)(pn + 131072);
        bf16x8 N2 = *(const bf16x8*)(pn + 65536);
        bf16x8 N3 = *(const bf16x8*)(pn + 196608);

        // ---- A fragments from LDS (conflict-free b128), current body
        const int chb = (s * 4 + l4) * 640;
        bf16x8 A[5];
        #pragma unroll
        for (int t = 0; t < 5; ++t) {
            int rr = j0a + t * 16 + l15;               // <= 94
            rr = (rr < 80) ? rr : 0;                   // OOB -> zero-row
            A[t] = *(const bf16x8*)&S_l[chb + rr * 8];
        }

        // ---- T19 prescription: loads at the body top, then MFMA cluster
        // with VALU (next body's address math) interleaved into its shadow.
        __builtin_amdgcn_sched_group_barrier(0x020, 4, 0);  // 4 VMEM reads (B n+1)
        __builtin_amdgcn_sched_group_barrier(0x100, 5, 0);  // 5 DS reads  (A n)
        #pragma unroll
        for (int g = 0; g < 6; ++g) {
            __builtin_amdgcn_sched_group_barrier(0x008, 3, 0);  // 3 MFMA
            __builtin_amdgcn_sched_group_barrier(0x002, 3, 0);  // 3 VALU fill
        }

        // ---- 18 MFMAs on the CURRENT (previously prefetched) B-fragments
        #pragma unroll
        for (int t = 0; t < 5; ++t) {
            acc[t][0] = __builtin_amdgcn_mfma_f32_16x16x32_bf16(A[t], C0, acc[t][0], 0, 0, 0);
            acc[t][1] = __builtin_amdgcn_mfma_f32_16x16x32_bf16(A[t], C1, acc[t][1], 0, 0, 0);
        }
        #pragma unroll
        for (int t = 1; t < 5; ++t) {
            acc[t - 1][0] = __builtin_amdgcn_mfma_f32_16x16x32_bf16(A[t], C2, acc[t - 1][0], 0, 0, 0);
            acc[t - 1][1] = __builtin_amdgcn_mfma_f32_16x16x32_bf16(A[t], C3, acc[t - 1][1], 0, 0, 0);
        }

        C0 = N0; C1 = N1; C2 = N2; C3 = N3;
    }

    // ---- merge 4 wave-partials in LDS, then atomic-add into out
    __syncthreads();
    {
        float* pw = Pw + wave * 2560;                  // [iv 32][x 80]
        #pragma unroll
        for (int m = 0; m < 5; ++m)
            #pragma unroll
            for (int n = 0; n < 2; ++n)
                *(f32x4*)&pw[(n * 16 + l15) * 80 + m * 16 + l4 * 4] = acc[m][n];
    }
    __syncthreads();
    for (int e = tid; e < 65 * 32; e += 256) {
        int x = e % 65, i = e / 65;
        int y = d - i + 16;
        if ((unsigned)y < 65u) {
            float v = Pw[0 * 2560 + i * 80 + x] + Pw[1 * 2560 + i * 80 + x]
                    + Pw[2 * 2560 + i * 80 + x] + Pw[3 * 2560 + i * 80 + x];
            atomicAdd(out + ((size_t)b * 4225 + (size_t)y * 65 + x), v);
        }
    }
}

// ---------------------------------------------------------------------------
// fp32 fallback (only if workspace is too small) — slow but exact
// ---------------------------------------------------------------------------
__global__ __launch_bounds__(256) void naive_kernel(const float* __restrict__ Q,
                                                    const float* __restrict__ S,
                                                    float* __restrict__ out) {
    int gid = blockIdx.x * 256 + threadIdx.x;
    if (gid >= 67600) return;
    int b = gid / 4225, r = gid % 4225, y = r / 65, x = r % 65;
    int jlo = 16 - x; if (jlo < 0) jlo = 0;
    int jhi = 80 - x; if (jhi > 32) jhi = 32;
    float acc = 0.f;
    for (int c = 0; c < 256; ++c) {
        const float* Sb = S + ((size_t)(b * 256 + c)) * 4096;
        const float* Qb = Q + ((size_t)(b * 256 + c)) * 1024;
        for (int i = 0; i < 32; ++i) {
            int dd = y + i - 16;
            if ((unsigned)dd >= 64u) continue;
            const float* Sr = Sb + dd * 64 + (x - 16);
            const float* Qr = Qb + i * 32;
            for (int j = jlo; j < jhi; ++j) acc += Sr[j] * Qr[j];
        }
    }
    out[gid] = acc;
}

extern "C" void kernel_launch(void* const* d_in, const int* in_sizes, int n_in,
                              void* d_out, int out_size, void* d_ws, size_t ws_size,
                              hipStream_t stream) {
    (void)in_sizes; (void)n_in; (void)out_size;
    const float* Q = (const float*)d_in[0];   // [16,256,32,32] f32
    const float* S = (const float*)d_in[1];   // [16,256,64,64] f32
    float* out = (float*)d_out;               // [16,1,65,65] f32

    const size_t QT_BYTES = (size_t)16 * 2 * 32 * 32 * 16 * 8 * 2;  // 8,388,608

    if (ws_size < QT_BYTES) {
        naive_kernel<<<(67600 + 255) / 256, 256, 0, stream>>>(Q, S, out);
        return;
    }
    uint16_t* Qt = (uint16_t*)d_ws;

    qtrans_kernel<<<dim3(32, 16), 256, 0, stream>>>(Q, Qt, out);
    corr_kernel<<<1024, 256, 0, stream>>>(S, Qt, out);
}